// Round 4
// baseline (42.714 us; speedup 1.0000x reference)
//
#include <hip/hip_runtime.h>

typedef __bf16 bf16x8 __attribute__((ext_vector_type(8)));
typedef float  f32x16 __attribute__((ext_vector_type(16)));

constexpr int Sn  = 2048;
constexpr int Dh  = 64;
constexpr int QT  = 32;   // q rows per tile
constexpr int KVT = 32;   // keys per kv tile
constexpr int NBH = 16;   // B*H
constexpr int NT  = Sn / QT;   // 64 tiles
constexpr int NW  = 8;    // waves per WG (split over KV)

// 1/sqrt(64) * log2(e): QK^T scores land directly in log2 domain -> p = v_exp_f32(st-m)
constexpr float SCL = 0.125f * 1.44269504088896340736f;

constexpr size_t ELEMS  = (size_t)NBH * Sn * Dh;
constexpr size_t QB_OFF = 0;            // bf16 Q, row-major, scale folded
constexpr size_t KP_OFF = ELEMS;        // bf16 K, fragment-packed
constexpr size_t VP_OFF = 2 * ELEMS;    // bf16 V, fragment-packed
constexpr size_t WS_NEED = 3 * ELEMS * 2;

__device__ inline bf16x8 cvt8(float4 a, float4 b, float s) {
  bf16x8 r;
  r[0] = (__bf16)(a.x * s); r[1] = (__bf16)(a.y * s);
  r[2] = (__bf16)(a.z * s); r[3] = (__bf16)(a.w * s);
  r[4] = (__bf16)(b.x * s); r[5] = (__bf16)(b.y * s);
  r[6] = (__bf16)(b.z * s); r[7] = (__bf16)(b.w * s);
  return r;
}

// One WG per (bh, kv-tile): converts Q slice (scaled by 1/8*log2e), packs K and V
// tiles into exact per-lane MFMA fragment order.
// Kp[g][c][lane][8]    = K[t0+ln][16c+8hi+i]
// Vp[g][2dt+T][lane][8] = V[t0+16T+4hi+(i&3)+8(i>>2)][32dt+ln]
__global__ __launch_bounds__(256) void prep(
    const float* __restrict__ q, const float* __restrict__ k,
    const float* __restrict__ v, __bf16* __restrict__ ws)
{
  __shared__ float tl[KVT][Dh + 1];
  const int g    = blockIdx.x;        // bh*64 + kt
  const int tid  = threadIdx.x;
  const int wv   = tid >> 6;
  const int lane = tid & 63;
  const int hi   = lane >> 5;
  const int ln   = lane & 31;
  const size_t tbase = (size_t)g * (KVT * Dh);

  { // Q: convert + fold scale*log2e
    const float* qp = q + tbase + (size_t)tid * 8;
    const float4 a = *(const float4*)qp;
    const float4 b = *(const float4*)(qp + 4);
    *(bf16x8*)(ws + QB_OFF + tbase + (size_t)tid * 8) = cvt8(a, b, SCL);
  }
  { // stage K tile -> LDS
    const float* kp = k + tbase;
#pragma unroll
    for (int e = 0; e < 2; ++e) {
      const int i4  = tid + e * 256;
      const float4 x = *(const float4*)(kp + (size_t)i4 * 4);
      const int row = i4 >> 4, col = (i4 & 15) * 4;
      tl[row][col] = x.x; tl[row][col + 1] = x.y;
      tl[row][col + 2] = x.z; tl[row][col + 3] = x.w;
    }
  }
  __syncthreads();
  { // pack K: wave wv = chunk c
    bf16x8 r;
#pragma unroll
    for (int i = 0; i < 8; ++i) r[i] = (__bf16)tl[ln][16 * wv + 8 * hi + i];
    *(bf16x8*)(ws + KP_OFF + ((size_t)(g * 4 + wv) * 64 + lane) * 8) = r;
  }
  __syncthreads();
  { // stage V tile -> LDS
    const float* vp = v + tbase;
#pragma unroll
    for (int e = 0; e < 2; ++e) {
      const int i4  = tid + e * 256;
      const float4 x = *(const float4*)(vp + (size_t)i4 * 4);
      const int row = i4 >> 4, col = (i4 & 15) * 4;
      tl[row][col] = x.x; tl[row][col + 1] = x.y;
      tl[row][col + 2] = x.z; tl[row][col + 3] = x.w;
    }
  }
  __syncthreads();
  { // pack V: wave wv = dt*2 + T
    const int dt = wv >> 1, T = wv & 1;
    bf16x8 r;
#pragma unroll
    for (int i = 0; i < 8; ++i) {
      const int row = 16 * T + 4 * hi + (i & 3) + 8 * (i >> 2);
      r[i] = (__bf16)tl[row][32 * dt + ln];
    }
    *(bf16x8*)(ws + VP_OFF + ((size_t)(g * 4 + wv) * 64 + lane) * 8) = r;
  }
}

// Split-KV attention on packed bf16. One WG (8 waves) per (bh, tile-PAIR):
// processes q-tile pr then 63-pr -> every WG owns exactly 65 kv-tile units,
// grid 512 = exactly 2 WGs/CU resident, zero tail imbalance.
// Softmax in log2 domain with defer-max (THR=8 -> P<=256, bf16-safe).
__global__ __launch_bounds__(512) void attn_bf16(
    const __bf16* __restrict__ ws, float* __restrict__ og)
{
  __shared__ __bf16 ldsO[NW][QT][Dh];   // 32 KB
  __shared__ float  ldsM[NW][QT];
  __shared__ float  ldsL[NW][QT];

  const int g    = blockIdx.x;
  const int bh   = g & 15;
  const int pr   = g >> 4;            // 0..31
  const int tid  = threadIdx.x;
  const int w    = tid >> 6;
  const int lane = tid & 63;
  const int hi   = lane >> 5;
  const int ln   = lane & 31;

  const __bf16* qB  = ws + QB_OFF + (size_t)bh * Sn * Dh;
  const __bf16* kpB = ws + KP_OFF + (size_t)bh * NT * (4 * 64 * 8);
  const __bf16* vpB = ws + VP_OFF + (size_t)bh * NT * (4 * 64 * 8);

  for (int ph = 0; ph < 2; ++ph) {
    const int tile = ph ? (63 - pr) : pr;

    // Q fragments (B operand): lane n=s=ln, k=16c+8hi+i; scale folded
    bf16x8 qf[4];
    {
      const __bf16* qp = qB + ((size_t)(tile * QT + ln)) * Dh + 8 * hi;
#pragma unroll
      for (int c = 0; c < 4; ++c) qf[c] = *(const bf16x8*)(qp + 16 * c);
    }

    f32x16 o0, o1;
#pragma unroll
    for (int i = 0; i < 16; ++i) { o0[i] = 0.f; o1[i] = 0.f; }
    float m = -1e30f, lsum = 0.f;

    for (int kt = w; kt <= tile; kt += NW) {
      const __bf16* kp = kpB + (size_t)kt * (4 * 64 * 8) + lane * 8;
      const bf16x8 kf0 = *(const bf16x8*)(kp);
      const bf16x8 kf1 = *(const bf16x8*)(kp + 64 * 8);
      const bf16x8 kf2 = *(const bf16x8*)(kp + 2 * 64 * 8);
      const bf16x8 kf3 = *(const bf16x8*)(kp + 3 * 64 * 8);
      const __bf16* vp = vpB + (size_t)kt * (4 * 64 * 8) + lane * 8;
      const bf16x8 v00 = *(const bf16x8*)(vp);
      const bf16x8 v01 = *(const bf16x8*)(vp + 64 * 8);
      const bf16x8 v10 = *(const bf16x8*)(vp + 2 * 64 * 8);
      const bf16x8 v11 = *(const bf16x8*)(vp + 3 * 64 * 8);

      f32x16 st;
#pragma unroll
      for (int i = 0; i < 16; ++i) st[i] = 0.f;
      st = __builtin_amdgcn_mfma_f32_32x32x16_bf16(kf0, qf[0], st, 0, 0, 0);
      st = __builtin_amdgcn_mfma_f32_32x32x16_bf16(kf1, qf[1], st, 0, 0, 0);
      st = __builtin_amdgcn_mfma_f32_32x32x16_bf16(kf2, qf[2], st, 0, 0, 0);
      st = __builtin_amdgcn_mfma_f32_32x32x16_bf16(kf3, qf[3], st, 0, 0, 0);

      // causal mask (diagonal tile only): entry (t_local=crow(r,hi), s_local=ln)
      if (kt == tile) {
#pragma unroll
        for (int r = 0; r < 16; ++r) {
          const int tl = (r & 3) + 8 * (r >> 2) + 4 * hi;
          if (tl > ln) st[r] = -1e30f;
        }
      }

      // row max: lane-local 16 + one xor-32 combine (row s=ln spans hi halves)
      float tmax = st[0];
#pragma unroll
      for (int r = 1; r < 16; ++r) tmax = fmaxf(tmax, st[r]);
      tmax = fmaxf(tmax, __shfl_xor(tmax, 32));

      // defer-max: rescale only if some row grew past THR=8 (log2) -> P <= 256
      if (__any(tmax > m + 8.0f)) {
        const float mnew = fmaxf(m, tmax);
        const float corr = exp2f(m - mnew);
        lsum *= corr;
#pragma unroll
        for (int r = 0; r < 16; ++r) {
          const float cr = __shfl(corr, (r & 3) + 8 * (r >> 2) + 4 * hi);
          o0[r] *= cr; o1[r] *= cr;
        }
        m = mnew;
      }

      float p[16];
      float psum = 0.f;
#pragma unroll
      for (int r = 0; r < 16; ++r) { p[r] = exp2f(st[r] - m); psum += p[r]; }
      psum += __shfl_xor(psum, 32);
      lsum += psum;

      // P A-fragments: slot (hi,i) of chunk T = p[8T+i] (same tau as V packing)
      bf16x8 pa0, pa1;
#pragma unroll
      for (int i = 0; i < 8; ++i) { pa0[i] = (__bf16)p[i]; pa1[i] = (__bf16)p[8 + i]; }

      o0 = __builtin_amdgcn_mfma_f32_32x32x16_bf16(pa0, v00, o0, 0, 0, 0);
      o1 = __builtin_amdgcn_mfma_f32_32x32x16_bf16(pa0, v10, o1, 0, 0, 0);
      o0 = __builtin_amdgcn_mfma_f32_32x32x16_bf16(pa1, v01, o0, 0, 0, 0);
      o1 = __builtin_amdgcn_mfma_f32_32x32x16_bf16(pa1, v11, o1, 0, 0, 0);
    }

    // publish partials (O rows are crow(r,hi); m,l live at row ln in both halves)
#pragma unroll
    for (int r = 0; r < 16; ++r) {
      const int rl = (r & 3) + 8 * (r >> 2) + 4 * hi;
      ldsO[w][rl][ln]      = (__bf16)o0[r];
      ldsO[w][rl][32 + ln] = (__bf16)o1[r];
    }
    if (hi == 0) { ldsM[w][ln] = m; ldsL[w][ln] = lsum; }
    __syncthreads();

    // combine 8 partials: 2048 outputs over 512 threads
#pragma unroll
    for (int e = 0; e < 4; ++e) {
      const int i   = e * 512 + tid;
      const int row = i >> 6;
      const int col = i & 63;
      float M = -1e30f;
#pragma unroll
      for (int wv = 0; wv < NW; ++wv) M = fmaxf(M, ldsM[wv][row]);
      float L = 0.f, o = 0.f;
#pragma unroll
      for (int wv = 0; wv < NW; ++wv) {
        const float ew = exp2f(ldsM[wv][row] - M);
        L += ldsL[wv][row] * ew;
        o += (float)ldsO[wv][row][col] * ew;
      }
      og[((size_t)bh * Sn + tile * QT + row) * Dh + col] = o / L;
    }
    __syncthreads();   // LDS reused by next phase's publish
  }
}

// ---------------- fallback (fp32 direct, used only if ws too small) ----------
__global__ __launch_bounds__(256) void attn_f32(
    const float* __restrict__ qg, const float* __restrict__ kg,
    const float* __restrict__ vg, float* __restrict__ og)
{
  __shared__ float ldsO[4][QT][Dh];
  __shared__ float ldsM[4][QT];
  __shared__ float ldsL[4][QT];

  const int g    = blockIdx.x;
  const int bh   = g >> 6;
  const int idx  = g & 63;
  const int tile = (idx & 1) ? (63 - (idx >> 1)) : (idx >> 1);
  const int w    = threadIdx.x >> 6;
  const int lane = threadIdx.x & 63;
  const int hi   = lane >> 5;
  const int ln   = lane & 31;

  const size_t base = (size_t)bh * Sn * Dh;
  const float* Q = qg + base;
  const float* K = kg + base;
  const float* V = vg + base;
  float*       O = og + base;
  const int srow = tile * QT + ln;

  bf16x8 qf[4];
  {
    const float* qp = Q + (size_t)srow * Dh + 8 * hi;
#pragma unroll
    for (int c = 0; c < 4; ++c) {
      const float4 x = *(const float4*)(qp + 16 * c);
      const float4 y = *(const float4*)(qp + 16 * c + 4);
      qf[c] = cvt8(x, y, 0.125f);
    }
  }
  f32x16 o0, o1;
#pragma unroll
  for (int i = 0; i < 16; ++i) { o0[i] = 0.f; o1[i] = 0.f; }
  float m = -1e30f, lsum = 0.f;

  for (int kt = w; kt <= tile; kt += 4) {
    const int t0 = kt * KVT;
    bf16x8 kf[4];
    const float* kp = K + (size_t)(t0 + ln) * Dh + 8 * hi;
#pragma unroll
    for (int c = 0; c < 4; ++c) {
      const float4 x = *(const float4*)(kp + 16 * c);
      const float4 y = *(const float4*)(kp + 16 * c + 4);
      kf[c] = cvt8(x, y, 1.0f);
    }
    f32x16 st;
#pragma unroll
    for (int i = 0; i < 16; ++i) st[i] = 0.f;
#pragma unroll
    for (int c = 0; c < 4; ++c)
      st = __builtin_amdgcn_mfma_f32_32x32x16_bf16(kf[c], qf[c], st, 0, 0, 0);
    if (kt == tile) {
#pragma unroll
      for (int r = 0; r < 16; ++r) {
        const int tl = (r & 3) + 8 * (r >> 2) + 4 * hi;
        if (tl > ln) st[r] = -1e30f;
      }
    }
    float tmax = st[0];
#pragma unroll
    for (int r = 1; r < 16; ++r) tmax = fmaxf(tmax, st[r]);
    tmax = fmaxf(tmax, __shfl_xor(tmax, 32));
    const float mnew = fmaxf(m, tmax);
    const bool  resc = __any(mnew > m);
    const float corr = __expf(m - mnew);
    m = mnew;
    float p[16];
    float psum = 0.f;
#pragma unroll
    for (int r = 0; r < 16; ++r) { p[r] = __expf(st[r] - mnew); psum += p[r]; }
    psum += __shfl_xor(psum, 32);
    lsum = lsum * corr + psum;
    if (resc) {
#pragma unroll
      for (int r = 0; r < 16; ++r) {
        const float cr = __shfl(corr, (r & 3) + 8 * (r >> 2) + 4 * hi);
        o0[r] *= cr; o1[r] *= cr;
      }
    }
    bf16x8 pa0, pa1;
#pragma unroll
    for (int i = 0; i < 8; ++i) { pa0[i] = (__bf16)p[i]; pa1[i] = (__bf16)p[8 + i]; }
#pragma unroll
    for (int T = 0; T < 2; ++T) {
      const int tb = t0 + 16 * T + 4 * hi;
      bf16x8 vb0, vb1;
#pragma unroll
      for (int j = 0; j < 4; ++j) {
        const float* vp  = V + (size_t)(tb + j) * Dh + ln;
        const float* vp2 = V + (size_t)(tb + 8 + j) * Dh + ln;
        vb0[j]     = (__bf16)vp[0];
        vb1[j]     = (__bf16)vp[32];
        vb0[4 + j] = (__bf16)vp2[0];
        vb1[4 + j] = (__bf16)vp2[32];
      }
      const bf16x8 pa = T ? pa1 : pa0;
      o0 = __builtin_amdgcn_mfma_f32_32x32x16_bf16(pa, vb0, o0, 0, 0, 0);
      o1 = __builtin_amdgcn_mfma_f32_32x32x16_bf16(pa, vb1, o1, 0, 0, 0);
    }
  }
#pragma unroll
  for (int r = 0; r < 16; ++r) {
    const int rl = (r & 3) + 8 * (r >> 2) + 4 * hi;
    ldsO[w][rl][ln]      = o0[r];
    ldsO[w][rl][32 + ln] = o1[r];
  }
  if (hi == 0) { ldsM[w][ln] = m; ldsL[w][ln] = lsum; }
  __syncthreads();
  const int tid = threadIdx.x;
#pragma unroll
  for (int e = 0; e < 8; ++e) {
    const int i   = e * 256 + tid;
    const int row = i >> 6;
    const int col = i & 63;
    const float m0 = ldsM[0][row], m1 = ldsM[1][row], m2 = ldsM[2][row], m3 = ldsM[3][row];
    const float M  = fmaxf(fmaxf(m0, m1), fmaxf(m2, m3));
    const float e0 = __expf(m0 - M), e1 = __expf(m1 - M), e2 = __expf(m2 - M), e3 = __expf(m3 - M);
    const float L  = ldsL[0][row] * e0 + ldsL[1][row] * e1 + ldsL[2][row] * e2 + ldsL[3][row] * e3;
    const float o  = ldsO[0][row][col] * e0 + ldsO[1][row][col] * e1
                   + ldsO[2][row][col] * e2 + ldsO[3][row][col] * e3;
    O[(size_t)(tile * QT + row) * Dh + col] = o / L;
  }
}

extern "C" void kernel_launch(void* const* d_in, const int* in_sizes, int n_in,
                              void* d_out, int out_size, void* d_ws, size_t ws_size,
                              hipStream_t stream) {
  const float* q = (const float*)d_in[0];
  const float* k = (const float*)d_in[1];
  const float* v = (const float*)d_in[2];
  float* out = (float*)d_out;
  if (ws_size >= WS_NEED) {
    prep<<<dim3(NBH * NT), dim3(256), 0, stream>>>(q, k, v, (__bf16*)d_ws);
    attn_bf16<<<dim3(NBH * NT / 2), dim3(512), 0, stream>>>((const __bf16*)d_ws, out);
  } else {
    attn_f32<<<dim3(1024), dim3(256), 0, stream>>>(q, k, v, out);
  }
}

// Round 5
// 40.050 us; speedup vs baseline: 1.0665x; 1.0665x over previous
//
#include <hip/hip_runtime.h>

typedef __bf16 bf16x8 __attribute__((ext_vector_type(8)));
typedef float  f32x16 __attribute__((ext_vector_type(16)));

constexpr int Sn  = 2048;
constexpr int Dh  = 64;
constexpr int QT  = 32;   // q rows per tile
constexpr int KVT = 32;   // keys per kv tile
constexpr int NBH = 16;   // B*H
constexpr int NT  = Sn / QT;   // 64 tiles
constexpr int NW  = 8;    // waves per WG (split over KV)

// 1/sqrt(64) * log2(e): QK^T scores land directly in log2 domain -> p = v_exp_f32(st-m)
constexpr float SCL = 0.125f * 1.44269504088896340736f;

constexpr size_t ELEMS  = (size_t)NBH * Sn * Dh;
constexpr size_t QB_OFF = 0;            // bf16 Q, row-major, scale folded
constexpr size_t KP_OFF = ELEMS;        // bf16 K, fragment-packed
constexpr size_t VP_OFF = 2 * ELEMS;    // bf16 V, fragment-packed
constexpr size_t WS_NEED = 3 * ELEMS * 2;

__device__ inline bf16x8 cvt8(float4 a, float4 b, float s) {
  bf16x8 r;
  r[0] = (__bf16)(a.x * s); r[1] = (__bf16)(a.y * s);
  r[2] = (__bf16)(a.z * s); r[3] = (__bf16)(a.w * s);
  r[4] = (__bf16)(b.x * s); r[5] = (__bf16)(b.y * s);
  r[6] = (__bf16)(b.z * s); r[7] = (__bf16)(b.w * s);
  return r;
}

// One WG per (bh, kv-tile): converts Q slice (scaled by 1/8*log2e), packs K and V
// tiles into exact per-lane MFMA fragment order.
// Kp[g][c][lane][8]     = K[t0+ln][16c+8hi+i]
// Vp[g][2dt+T][lane][8] = V[t0+16T+4hi+(i&3)+8(i>>2)][32dt+ln]
__global__ __launch_bounds__(256) void prep(
    const float* __restrict__ q, const float* __restrict__ k,
    const float* __restrict__ v, __bf16* __restrict__ ws)
{
  __shared__ float tl[KVT][Dh + 1];
  const int g    = blockIdx.x;        // bh*64 + kt
  const int tid  = threadIdx.x;
  const int wv   = tid >> 6;
  const int lane = tid & 63;
  const int hi   = lane >> 5;
  const int ln   = lane & 31;
  const size_t tbase = (size_t)g * (KVT * Dh);

  { // Q: convert + fold scale*log2e
    const float* qp = q + tbase + (size_t)tid * 8;
    const float4 a = *(const float4*)qp;
    const float4 b = *(const float4*)(qp + 4);
    *(bf16x8*)(ws + QB_OFF + tbase + (size_t)tid * 8) = cvt8(a, b, SCL);
  }
  { // stage K tile -> LDS
    const float* kp = k + tbase;
#pragma unroll
    for (int e = 0; e < 2; ++e) {
      const int i4  = tid + e * 256;
      const float4 x = *(const float4*)(kp + (size_t)i4 * 4);
      const int row = i4 >> 4, col = (i4 & 15) * 4;
      tl[row][col] = x.x; tl[row][col + 1] = x.y;
      tl[row][col + 2] = x.z; tl[row][col + 3] = x.w;
    }
  }
  __syncthreads();
  { // pack K: wave wv = chunk c
    bf16x8 r;
#pragma unroll
    for (int i = 0; i < 8; ++i) r[i] = (__bf16)tl[ln][16 * wv + 8 * hi + i];
    *(bf16x8*)(ws + KP_OFF + ((size_t)(g * 4 + wv) * 64 + lane) * 8) = r;
  }
  __syncthreads();
  { // stage V tile -> LDS
    const float* vp = v + tbase;
#pragma unroll
    for (int e = 0; e < 2; ++e) {
      const int i4  = tid + e * 256;
      const float4 x = *(const float4*)(vp + (size_t)i4 * 4);
      const int row = i4 >> 4, col = (i4 & 15) * 4;
      tl[row][col] = x.x; tl[row][col + 1] = x.y;
      tl[row][col + 2] = x.z; tl[row][col + 3] = x.w;
    }
  }
  __syncthreads();
  { // pack V: wave wv = dt*2 + T
    const int dt = wv >> 1, T = wv & 1;
    bf16x8 r;
#pragma unroll
    for (int i = 0; i < 8; ++i) {
      const int row = 16 * T + 4 * hi + (i & 3) + 8 * (i >> 2);
      r[i] = (__bf16)tl[row][32 * dt + ln];
    }
    *(bf16x8*)(ws + VP_OFF + ((size_t)(g * 4 + wv) * 64 + lane) * 8) = r;
  }
}

// Split-KV attention on packed bf16. One WG (8 waves) per (bh, tile-PAIR):
// processes q-tile pr then 63-pr -> every WG owns exactly 65 kv-tile units.
// XCD pinning: xcd = b%8 (HK round-robin mapping) -> heads {2x, 2x+1} live on
// xcd x only; per-XCD K/V working set = 1 MB, fully L2-resident.
__global__ __launch_bounds__(512, 4) void attn_bf16(
    const __bf16* __restrict__ ws, float* __restrict__ og)
{
  __shared__ __bf16 ldsO[NW][QT][Dh];   // 32 KB
  __shared__ float  ldsM[NW][QT];
  __shared__ float  ldsL[NW][QT];

  const int b    = blockIdx.x;            // 0..511
  const int bh   = 2 * (b & 7) + ((b >> 3) & 1);  // head pinned to XCD b%8
  const int pr   = b >> 4;                // 0..31
  const int tid  = threadIdx.x;
  const int w    = tid >> 6;
  const int lane = tid & 63;
  const int hi   = lane >> 5;
  const int ln   = lane & 31;

  const __bf16* qB  = ws + QB_OFF + (size_t)bh * Sn * Dh;
  const __bf16* kpB = ws + KP_OFF + (size_t)bh * NT * (4 * 64 * 8);
  const __bf16* vpB = ws + VP_OFF + (size_t)bh * NT * (4 * 64 * 8);

  for (int ph = 0; ph < 2; ++ph) {
    const int tile = ph ? (63 - pr) : pr;

    // Q fragments (B operand): lane n=s=ln, k=16c+8hi+i; scale folded
    bf16x8 qf[4];
    {
      const __bf16* qp = qB + ((size_t)(tile * QT + ln)) * Dh + 8 * hi;
#pragma unroll
      for (int c = 0; c < 4; ++c) qf[c] = *(const bf16x8*)(qp + 16 * c);
    }

    f32x16 o0, o1;
#pragma unroll
    for (int i = 0; i < 16; ++i) { o0[i] = 0.f; o1[i] = 0.f; }
    float m = -1e30f, lsum = 0.f;

    for (int kt = w; kt <= tile; kt += NW) {
      const __bf16* kp = kpB + (size_t)kt * (4 * 64 * 8) + lane * 8;
      const bf16x8 kf0 = *(const bf16x8*)(kp);
      const bf16x8 kf1 = *(const bf16x8*)(kp + 64 * 8);
      const bf16x8 kf2 = *(const bf16x8*)(kp + 2 * 64 * 8);
      const bf16x8 kf3 = *(const bf16x8*)(kp + 3 * 64 * 8);
      const __bf16* vp = vpB + (size_t)kt * (4 * 64 * 8) + lane * 8;
      const bf16x8 v00 = *(const bf16x8*)(vp);
      const bf16x8 v01 = *(const bf16x8*)(vp + 64 * 8);
      const bf16x8 v10 = *(const bf16x8*)(vp + 2 * 64 * 8);
      const bf16x8 v11 = *(const bf16x8*)(vp + 3 * 64 * 8);

      f32x16 st;
#pragma unroll
      for (int i = 0; i < 16; ++i) st[i] = 0.f;
      st = __builtin_amdgcn_mfma_f32_32x32x16_bf16(kf0, qf[0], st, 0, 0, 0);
      st = __builtin_amdgcn_mfma_f32_32x32x16_bf16(kf1, qf[1], st, 0, 0, 0);
      st = __builtin_amdgcn_mfma_f32_32x32x16_bf16(kf2, qf[2], st, 0, 0, 0);
      st = __builtin_amdgcn_mfma_f32_32x32x16_bf16(kf3, qf[3], st, 0, 0, 0);

      // causal mask (diagonal tile only): entry (t_local=crow(r,hi), s_local=ln)
      if (kt == tile) {
#pragma unroll
        for (int r = 0; r < 16; ++r) {
          const int tl = (r & 3) + 8 * (r >> 2) + 4 * hi;
          if (tl > ln) st[r] = -1e30f;
        }
      }

      // row max: lane-local 16 (tree) + one xor-32 combine
      float mx01 = fmaxf(st[0], st[1]),   mx23 = fmaxf(st[2], st[3]);
      float mx45 = fmaxf(st[4], st[5]),   mx67 = fmaxf(st[6], st[7]);
      float mx89 = fmaxf(st[8], st[9]),   mxab = fmaxf(st[10], st[11]);
      float mxcd = fmaxf(st[12], st[13]), mxef = fmaxf(st[14], st[15]);
      float tmax = fmaxf(fmaxf(fmaxf(mx01, mx23), fmaxf(mx45, mx67)),
                         fmaxf(fmaxf(mx89, mxab), fmaxf(mxcd, mxef)));
      tmax = fmaxf(tmax, __shfl_xor(tmax, 32));

      // defer-max: rescale only if some row grew past THR=8 (log2) -> P <= 256
      if (__any(tmax > m + 8.0f)) {
        const float mnew = fmaxf(m, tmax);
        const float corr = exp2f(m - mnew);
        lsum *= corr;
#pragma unroll
        for (int r = 0; r < 16; ++r) {
          const float cr = __shfl(corr, (r & 3) + 8 * (r >> 2) + 4 * hi);
          o0[r] *= cr; o1[r] *= cr;
        }
        m = mnew;
      }

      float p[16];
#pragma unroll
      for (int r = 0; r < 16; ++r) p[r] = exp2f(st[r] - m);
      // pairwise-tree psum (shorter dependent chain than serial adds)
      float s0 = (p[0]+p[1]) + (p[2]+p[3]),   s1 = (p[4]+p[5]) + (p[6]+p[7]);
      float s2 = (p[8]+p[9]) + (p[10]+p[11]), s3 = (p[12]+p[13]) + (p[14]+p[15]);
      float psum = (s0 + s1) + (s2 + s3);
      psum += __shfl_xor(psum, 32);
      lsum += psum;

      // P A-fragments: slot (hi,i) of chunk T = p[8T+i] (same tau as V packing)
      bf16x8 pa0, pa1;
#pragma unroll
      for (int i = 0; i < 8; ++i) { pa0[i] = (__bf16)p[i]; pa1[i] = (__bf16)p[8 + i]; }

      o0 = __builtin_amdgcn_mfma_f32_32x32x16_bf16(pa0, v00, o0, 0, 0, 0);
      o1 = __builtin_amdgcn_mfma_f32_32x32x16_bf16(pa0, v10, o1, 0, 0, 0);
      o0 = __builtin_amdgcn_mfma_f32_32x32x16_bf16(pa1, v01, o0, 0, 0, 0);
      o1 = __builtin_amdgcn_mfma_f32_32x32x16_bf16(pa1, v11, o1, 0, 0, 0);
    }

    // publish partials (O rows are crow(r,hi); m,l live at row ln in both halves)
#pragma unroll
    for (int r = 0; r < 16; ++r) {
      const int rl = (r & 3) + 8 * (r >> 2) + 4 * hi;
      ldsO[w][rl][ln]      = (__bf16)o0[r];
      ldsO[w][rl][32 + ln] = (__bf16)o1[r];
    }
    if (hi == 0) { ldsM[w][ln] = m; ldsL[w][ln] = lsum; }
    __syncthreads();

    // combine 8 partials: 2048 outputs over 512 threads
#pragma unroll
    for (int e = 0; e < 4; ++e) {
      const int i   = e * 512 + tid;
      const int row = i >> 6;
      const int col = i & 63;
      float M = -1e30f;
#pragma unroll
      for (int wv = 0; wv < NW; ++wv) M = fmaxf(M, ldsM[wv][row]);
      float L = 0.f, o = 0.f;
#pragma unroll
      for (int wv = 0; wv < NW; ++wv) {
        const float ew = exp2f(ldsM[wv][row] - M);
        L += ldsL[wv][row] * ew;
        o += (float)ldsO[wv][row][col] * ew;
      }
      og[((size_t)bh * Sn + tile * QT + row) * Dh + col] = o / L;
    }
    __syncthreads();   // LDS reused by next phase's publish
  }
}

// ---------------- fallback (fp32 direct, used only if ws too small) ----------
__global__ __launch_bounds__(256) void attn_f32(
    const float* __restrict__ qg, const float* __restrict__ kg,
    const float* __restrict__ vg, float* __restrict__ og)
{
  __shared__ float ldsO[4][QT][Dh];
  __shared__ float ldsM[4][QT];
  __shared__ float ldsL[4][QT];

  const int g    = blockIdx.x;
  const int bh   = g >> 6;
  const int idx  = g & 63;
  const int tile = (idx & 1) ? (63 - (idx >> 1)) : (idx >> 1);
  const int w    = threadIdx.x >> 6;
  const int lane = threadIdx.x & 63;
  const int hi   = lane >> 5;
  const int ln   = lane & 31;

  const size_t base = (size_t)bh * Sn * Dh;
  const float* Q = qg + base;
  const float* K = kg + base;
  const float* V = vg + base;
  float*       O = og + base;
  const int srow = tile * QT + ln;

  bf16x8 qf[4];
  {
    const float* qp = Q + (size_t)srow * Dh + 8 * hi;
#pragma unroll
    for (int c = 0; c < 4; ++c) {
      const float4 x = *(const float4*)(qp + 16 * c);
      const float4 y = *(const float4*)(qp + 16 * c + 4);
      qf[c] = cvt8(x, y, 0.125f);
    }
  }
  f32x16 o0, o1;
#pragma unroll
  for (int i = 0; i < 16; ++i) { o0[i] = 0.f; o1[i] = 0.f; }
  float m = -1e30f, lsum = 0.f;

  for (int kt = w; kt <= tile; kt += 4) {
    const int t0 = kt * KVT;
    bf16x8 kf[4];
    const float* kp = K + (size_t)(t0 + ln) * Dh + 8 * hi;
#pragma unroll
    for (int c = 0; c < 4; ++c) {
      const float4 x = *(const float4*)(kp + 16 * c);
      const float4 y = *(const float4*)(kp + 16 * c + 4);
      kf[c] = cvt8(x, y, 1.0f);
    }
    f32x16 st;
#pragma unroll
    for (int i = 0; i < 16; ++i) st[i] = 0.f;
#pragma unroll
    for (int c = 0; c < 4; ++c)
      st = __builtin_amdgcn_mfma_f32_32x32x16_bf16(kf[c], qf[c], st, 0, 0, 0);
    if (kt == tile) {
#pragma unroll
      for (int r = 0; r < 16; ++r) {
        const int tl = (r & 3) + 8 * (r >> 2) + 4 * hi;
        if (tl > ln) st[r] = -1e30f;
      }
    }
    float tmax = st[0];
#pragma unroll
    for (int r = 1; r < 16; ++r) tmax = fmaxf(tmax, st[r]);
    tmax = fmaxf(tmax, __shfl_xor(tmax, 32));
    const float mnew = fmaxf(m, tmax);
    const bool  resc = __any(mnew > m);
    const float corr = __expf(m - mnew);
    m = mnew;
    float p[16];
    float psum = 0.f;
#pragma unroll
    for (int r = 0; r < 16; ++r) { p[r] = __expf(st[r] - mnew); psum += p[r]; }
    psum += __shfl_xor(psum, 32);
    lsum = lsum * corr + psum;
    if (resc) {
#pragma unroll
      for (int r = 0; r < 16; ++r) {
        const float cr = __shfl(corr, (r & 3) + 8 * (r >> 2) + 4 * hi);
        o0[r] *= cr; o1[r] *= cr;
      }
    }
    bf16x8 pa0, pa1;
#pragma unroll
    for (int i = 0; i < 8; ++i) { pa0[i] = (__bf16)p[i]; pa1[i] = (__bf16)p[8 + i]; }
#pragma unroll
    for (int T = 0; T < 2; ++T) {
      const int tb = t0 + 16 * T + 4 * hi;
      bf16x8 vb0, vb1;
#pragma unroll
      for (int j = 0; j < 4; ++j) {
        const float* vp  = V + (size_t)(tb + j) * Dh + ln;
        const float* vp2 = V + (size_t)(tb + 8 + j) * Dh + ln;
        vb0[j]     = (__bf16)vp[0];
        vb1[j]     = (__bf16)vp[32];
        vb0[4 + j] = (__bf16)vp2[0];
        vb1[4 + j] = (__bf16)vp2[32];
      }
      const bf16x8 pa = T ? pa1 : pa0;
      o0 = __builtin_amdgcn_mfma_f32_32x32x16_bf16(pa, vb0, o0, 0, 0, 0);
      o1 = __builtin_amdgcn_mfma_f32_32x32x16_bf16(pa, vb1, o1, 0, 0, 0);
    }
  }
#pragma unroll
  for (int r = 0; r < 16; ++r) {
    const int rl = (r & 3) + 8 * (r >> 2) + 4 * hi;
    ldsO[w][rl][ln]      = o0[r];
    ldsO[w][rl][32 + ln] = o1[r];
  }
  if (hi == 0) { ldsM[w][ln] = m; ldsL[w][ln] = lsum; }
  __syncthreads();
  const int tid = threadIdx.x;
#pragma unroll
  for (int e = 0; e < 8; ++e) {
    const int i   = e * 256 + tid;
    const int row = i >> 6;
    const int col = i & 63;
    const float m0 = ldsM[0][row], m1 = ldsM[1][row], m2 = ldsM[2][row], m3 = ldsM[3][row];
    const float M  = fmaxf(fmaxf(m0, m1), fmaxf(m2, m3));
    const float e0 = __expf(m0 - M), e1 = __expf(m1 - M), e2 = __expf(m2 - M), e3 = __expf(m3 - M);
    const float L  = ldsL[0][row] * e0 + ldsL[1][row] * e1 + ldsL[2][row] * e2 + ldsL[3][row] * e3;
    const float o  = ldsO[0][row][col] * e0 + ldsO[1][row][col] * e1
                   + ldsO[2][row][col] * e2 + ldsO[3][row][col] * e3;
    O[(size_t)(tile * QT + row) * Dh + col] = o / L;
  }
}

extern "C" void kernel_launch(void* const* d_in, const int* in_sizes, int n_in,
                              void* d_out, int out_size, void* d_ws, size_t ws_size,
                              hipStream_t stream) {
  const float* q = (const float*)d_in[0];
  const float* k = (const float*)d_in[1];
  const float* v = (const float*)d_in[2];
  float* out = (float*)d_out;
  if (ws_size >= WS_NEED) {
    prep<<<dim3(NBH * NT), dim3(256), 0, stream>>>(q, k, v, (__bf16*)d_ws);
    attn_bf16<<<dim3(NBH * NT / 2), dim3(512), 0, stream>>>((const __bf16*)d_ws, out);
  } else {
    attn_f32<<<dim3(1024), dim3(256), 0, stream>>>(q, k, v, out);
  }
}